// Round 13
// baseline (4512.527 us; speedup 1.0000x reference)
//
#include <hip/hip_runtime.h>
#include <hip/hip_bf16.h>
#include <stdint.h>

#define B_  128
#define T_  784
#define H_  512
#define G4  2048
#define NC_ 10

#define GB 8     // batch groups (16 rows each)
#define GC 32    // column groups (16 h-cols each)
#define NWG (GB*GC)

typedef __bf16 bf16x8 __attribute__((ext_vector_type(8)));
typedef float  f32x4  __attribute__((ext_vector_type(4)));
typedef unsigned int       u32;
typedef unsigned long long u64;

static __device__ __forceinline__ float bf2f(unsigned short u){
  union { unsigned int i; float f; } v; v.i = ((unsigned int)u) << 16; return v.f;
}
static __device__ __forceinline__ unsigned short f2bf_rn(float f){
  union { float f; unsigned int i; } v; v.f = f;
  unsigned int x = v.i;
  unsigned int lsb = (x >> 16) & 1u;
  x += 0x7fffu + lsb;
  return (unsigned short)(x >> 16);
}

// fast gates: native v_exp_f32 / v_rcp_f32 (err ~1e-6; proven r3/r5/r9)
static __device__ __forceinline__ float fsig(float z){
  return __builtin_amdgcn_rcpf(1.f + __expf(-z));
}
static __device__ __forceinline__ float ftanh(float z){
  return 2.f * __builtin_amdgcn_rcpf(1.f + __expf(-2.f * z)) - 1.f;
}

// ---------------------------------------------------------------------------
// Prep: Wh [512][2048] f32 -> WhT_hi/lo [2048][512] bf16 planes (transposed).
// ---------------------------------------------------------------------------
__global__ void prep_wh(const float* __restrict__ Wh,
                        unsigned short* __restrict__ whT_hi,
                        unsigned short* __restrict__ whT_lo){
  int idx = blockIdx.x * blockDim.x + threadIdx.x;   // 0..131071
  int kb  = idx >> 11;        // 0..63  (k block of 8)
  int g   = idx & 2047;       // 0..2047 (lane-adjacent -> coalesced reads)
  int k0  = kb * 8;
  unsigned short hi8[8], lo8[8];
  #pragma unroll
  for (int j = 0; j < 8; ++j){
    float v = Wh[(size_t)(k0 + j) * G4 + g];
    unsigned short hi = f2bf_rn(v);
    hi8[j] = hi;
    lo8[j] = f2bf_rn(v - bf2f(hi));
  }
  *(uint4*)(whT_hi + (size_t)g * H_ + k0) = *(const uint4*)hi8;
  *(uint4*)(whT_lo + (size_t)g * H_ + k0) = *(const uint4*)lo8;
}

// ---------------------------------------------------------------------------
// Main recurrent scan — r9 exchange semantics with a shorter critical path:
// zbuf double-buffered (drops barrier2); each WAVE drains its own stores
// (s_waitcnt vmcnt(0), r8-proven) and increments the WG flag; consumers wait
// flag >= 4t. Double-pumped poll halves the observe quantum.
// ---------------------------------------------------------------------------
__global__ __launch_bounds__(256, 1) void scan_k(
    const float* __restrict__ x, const float* __restrict__ Wx,
    const float* __restrict__ bias,
    const unsigned short* __restrict__ whT_hi,
    const unsigned short* __restrict__ whT_lo,
    u32* __restrict__ hbp,               // [2][128][512] u32 = (hi<<16)|lo
    unsigned short* __restrict__ hs,     // [128][784][512] bf16
    u32* __restrict__ flags)             // [256] per-WG publish counter
{
  const int wg  = blockIdx.x;
  const int bg  = wg & 7;          // batch group
  const int cg  = wg >> 3;         // column group
  const int b0  = bg * 16;
  const int c0  = cg * 16;
  const int tid = threadIdx.x;
  const int wv  = tid >> 6;
  const int lane = tid & 63;
  const int nl  = lane & 15;       // A-row / B-col index within tile
  const int kc  = lane >> 4;       // k-chunk (0..3)

  __shared__ float xs[16 * 784];                          // 50176 B
  __shared__ __align__(16) unsigned short hhi[16 * 512];  // 16384 B (swizzled)
  __shared__ __align__(16) unsigned short hlo[16 * 512];  // 16384 B
  __shared__ float zbuf[2][16][16][17];                   // 34816 B (dbuf)

  // preload x slice for our 16 batch rows (contiguous in global)
  for (int i = tid; i < 16 * 784; i += 256) xs[i] = x[(size_t)b0 * 784 + i];

  // Wh fragments resident in registers
  bf16x8 bhi[4][4], blo[4][4];
  #pragma unroll
  for (int q = 0; q < 4; ++q){
    const int gcol = q * 512 + c0 + nl;
    const unsigned short* ph = whT_hi + (size_t)gcol * H_;
    const unsigned short* pl = whT_lo + (size_t)gcol * H_;
    #pragma unroll
    for (int kkl = 0; kkl < 4; ++kkl){
      int ko = (wv * 4 + kkl) * 32 + kc * 8;
      bhi[q][kkl] = *(const bf16x8*)(ph + ko);
      blo[q][kkl] = *(const bf16x8*)(pl + ko);
    }
  }

  const int r_  = tid >> 4;
  const int cl_ = tid & 15;
  float wx4[4], bb4[4];
  #pragma unroll
  for (int q = 0; q < 4; ++q){
    wx4[q] = Wx[q * 512 + c0 + cl_];
    bb4[q] = bias[q * 512 + c0 + cl_];
  }
  float c_st = 0.f;

  u32* const myflag = flags + (bg * 32 + cg);
  const u32* const grpflags = flags + bg * 32;

  __syncthreads();

  for (int t = 0; t < T_; ++t){
    const int par = t & 1;
    f32x4 zq[4];
    #pragma unroll
    for (int q = 0; q < 4; ++q) zq[q] = (f32x4){0.f, 0.f, 0.f, 0.f};

    if (t > 0){
      // ---- poll (double-pumped): all 32 WGs of bg at counter >= 4t ----
      {
        const u32 tgt = 4u * (u32)t;
        int guard = 0;
        for (;;){
          u32 v1 = 0xffffffffu, v2 = 0xffffffffu;
          if (lane < 32){
            v1 = __hip_atomic_load(grpflags + lane, __ATOMIC_RELAXED, __HIP_MEMORY_SCOPE_AGENT);
            v2 = __hip_atomic_load(grpflags + lane, __ATOMIC_RELAXED, __HIP_MEMORY_SCOPE_AGENT);
          }
          if (__all(v1 >= tgt)) break;
          if (__all(v2 >= tgt)) break;
          if (++guard > (1 << 21)) break;   // fail loudly, never hang
        }
        asm volatile("" ::: "memory");      // keep data loads after the poll
      }

      // ---- stage h (packed u32) from LLC: thread -> cols {2tid,2tid+1} ----
      const u64* hb8 = (const u64*)(hbp + (size_t)par * B_ * H_);
      u64 vv[16];
      #pragma unroll
      for (int j = 0; j < 16; ++j)
        vv[j] = __hip_atomic_load(hb8 + (size_t)(b0 + j) * 256 + tid,
                                  __ATOMIC_RELAXED, __HIP_MEMORY_SCOPE_AGENT);
      #pragma unroll
      for (int j = 0; j < 16; ++j){
        u32 a = (u32)vv[j], b = (u32)(vv[j] >> 32);
        u32 hip_ = (a >> 16) | (b & 0xffff0000u);
        u32 lop_ = (a & 0xffffu) | (b << 16);
        int off = (4 * tid) ^ ((j & 7) << 4);   // XOR swizzle, 4B-aligned safe
        *(u32*)((char*)hhi + j * 1024 + off) = hip_;
        *(u32*)((char*)hlo + j * 1024 + off) = lop_;
      }
      // wave wv stages exactly cols [128wv,128wv+128) = the only ones it reads.

      f32x4 ahh[4], ahl[4], alh[4];
      #pragma unroll
      for (int q = 0; q < 4; ++q){ ahh[q] = (f32x4){0,0,0,0}; ahl[q] = (f32x4){0,0,0,0}; alh[q] = (f32x4){0,0,0,0}; }

      const int base = nl * 1024;
      const int swz  = (nl & 7) << 4;
      #pragma unroll
      for (int kkl = 0; kkl < 4; ++kkl){
        int bo = (wv * 4 + kkl) * 64 + kc * 16;
        int ad = base + (bo ^ swz);
        bf16x8 ah = *(const bf16x8*)((const char*)hhi + ad);
        bf16x8 al = *(const bf16x8*)((const char*)hlo + ad);
        #pragma unroll
        for (int q = 0; q < 4; ++q){
          ahh[q] = __builtin_amdgcn_mfma_f32_16x16x32_bf16(ah, bhi[q][kkl], ahh[q], 0, 0, 0);
          ahl[q] = __builtin_amdgcn_mfma_f32_16x16x32_bf16(ah, blo[q][kkl], ahl[q], 0, 0, 0);
          alh[q] = __builtin_amdgcn_mfma_f32_16x16x32_bf16(al, bhi[q][kkl], alh[q], 0, 0, 0);
        }
      }
      #pragma unroll
      for (int q = 0; q < 4; ++q) zq[q] = ahh[q] + (ahl[q] + alh[q]);
    }

    // write K-partial z tiles: D layout col=lane&15, row=kc*4+i
    #pragma unroll
    for (int q = 0; q < 4; ++q){
      #pragma unroll
      for (int i = 0; i < 4; ++i) zbuf[par][wv * 4 + q][kc * 4 + i][nl] = zq[q][i];
    }
    __syncthreads();   // the ONLY barrier per step (zbuf double-buffered)

    // gates (fp32, fast exp/rcp) -- each thread owns (b0+r_, c0+cl_)
    unsigned short hi_keep;
    {
      float xv = xs[r_ * 784 + t];
      float zf = zbuf[par][0][r_][cl_] + zbuf[par][4][r_][cl_] + zbuf[par][8][r_][cl_]  + zbuf[par][12][r_][cl_] + xv * wx4[0] + bb4[0];
      float zr = zbuf[par][1][r_][cl_] + zbuf[par][5][r_][cl_] + zbuf[par][9][r_][cl_]  + zbuf[par][13][r_][cl_] + xv * wx4[1] + bb4[1];
      float zu = zbuf[par][2][r_][cl_] + zbuf[par][6][r_][cl_] + zbuf[par][10][r_][cl_] + zbuf[par][14][r_][cl_] + xv * wx4[2] + bb4[2];
      float zo = zbuf[par][3][r_][cl_] + zbuf[par][7][r_][cl_] + zbuf[par][11][r_][cl_] + zbuf[par][15][r_][cl_] + xv * wx4[3] + bb4[3];
      float f  = fsig(zf);
      float r  = fsig(zr);
      float omf = 1.f - f;
      float g  = r * (1.f - omf * omf) + (1.f - r) * (f * f);
      c_st = g * c_st + (1.f - g) * ftanh(zu);
      float h = fsig(zo) * ftanh(c_st);
      unsigned short hi = f2bf_rn(h);
      unsigned short lo = f2bf_rn(h - bf2f(hi));
      hi_keep = hi;
      u32 packed = ((u32)hi << 16) | (u32)lo;
      // publish h(t+1) via device-coherent store (LLC), no fence needed
      __hip_atomic_store(hbp + (size_t)((t + 1) & 1) * B_ * H_ +
                               (size_t)(b0 + r_) * H_ + (c0 + cl_),
                         packed, __ATOMIC_RELAXED, __HIP_MEMORY_SCOPE_AGENT);
    }

    // per-wave publish: drain THIS wave's stores (r8-proven), bump counter.
    asm volatile("s_waitcnt vmcnt(0)" ::: "memory");
    if (lane == 0)
      __hip_atomic_fetch_add(myflag, 1u, __ATOMIC_RELAXED, __HIP_MEMORY_SCOPE_AGENT);

    // hs store issued AFTER publish: drains under next step's poll+compute.
    hs[((size_t)(b0 + r_) * T_ + t) * H_ + (c0 + cl_)] = hi_keep;
  }
}

// ---------------------------------------------------------------------------
// MLP stage 1: partial GEMM, D[n][b] orientation. 256 WGs, K-chunk = 1568.
// ---------------------------------------------------------------------------
__global__ __launch_bounds__(256, 1) void mlp1_k(
    const unsigned short* __restrict__ hs,   // [128][401408] bf16
    const float* __restrict__ W1,            // [401408][256]
    float* __restrict__ partialT)            // [256 cm][256 n][128 b]
{
  const int cm  = blockIdx.x;
  const int tid = threadIdx.x;
  const int wv  = tid >> 6, lane = tid & 63;
  const int nl  = lane & 15, kc = lane >> 4;
  const int m_base = cm * 1568;

  f32x4 acc[4][8];
  #pragma unroll
  for (int i = 0; i < 4; ++i)
    #pragma unroll
    for (int j = 0; j < 8; ++j) acc[i][j] = (f32x4){0, 0, 0, 0};

  for (int ks = 0; ks < 49; ++ks){
    const int m0 = m_base + ks * 32 + kc * 8;
    bf16x8 bf[8];
    #pragma unroll
    for (int nt = 0; nt < 8; ++nt)
      bf[nt] = *(const bf16x8*)(hs + (size_t)(nt * 16 + nl) * 401408 + m0);

    #pragma unroll
    for (int mt = 0; mt < 4; ++mt){
      const int n = wv * 64 + mt * 16 + nl;
      union { bf16x8 v; unsigned short u[8]; } Ah, Al;
      #pragma unroll
      for (int j = 0; j < 8; ++j){
        float av = W1[(size_t)(m0 + j) * 256 + n];
        unsigned short hi = f2bf_rn(av);
        Ah.u[j] = hi;
        Al.u[j] = f2bf_rn(av - bf2f(hi));
      }
      #pragma unroll
      for (int nt = 0; nt < 8; ++nt){
        acc[mt][nt] = __builtin_amdgcn_mfma_f32_16x16x32_bf16(Ah.v, bf[nt], acc[mt][nt], 0, 0, 0);
        acc[mt][nt] = __builtin_amdgcn_mfma_f32_16x16x32_bf16(Al.v, bf[nt], acc[mt][nt], 0, 0, 0);
      }
    }
  }

  #pragma unroll
  for (int mt = 0; mt < 4; ++mt){
    const int n = wv * 64 + mt * 16 + kc * 4;
    #pragma unroll
    for (int nt = 0; nt < 8; ++nt){
      const int b = nt * 16 + nl;
      #pragma unroll
      for (int i = 0; i < 4; ++i)
        partialT[((size_t)cm * 256 + (n + i)) * 128 + b] = acc[mt][nt][i];
    }
  }
}

// MLP stage 2: reduce partials over 256 chunks, + b1, ReLU -> hiddenT [256][128]
__global__ void mlp2_k(const float* __restrict__ partialT,
                       const float* __restrict__ b1,
                       float* __restrict__ hiddenT){
  const int n = blockIdx.x;
  const int b = threadIdx.x;
  float s = 0.f;
  for (int cm = 0; cm < 256; ++cm)
    s += partialT[((size_t)cm * 256 + n) * 128 + b];
  s += b1[n];
  hiddenT[n * 128 + b] = s > 0.f ? s : 0.f;
}

// MLP stage 3: out[b][j] = b2[j] + sum_n hiddenT[n][b] * W2[n][j]
__global__ void mlp3_k(const float* __restrict__ hiddenT,
                       const float* __restrict__ W2,
                       const float* __restrict__ b2,
                       float* __restrict__ out){
  const int tid = threadIdx.x;
  for (int oi = tid; oi < B_ * NC_; oi += 256){
    int b = oi / NC_, j = oi % NC_;
    float s = b2[j];
    for (int n = 0; n < 256; ++n)
      s += hiddenT[n * 128 + b] * W2[n * NC_ + j];
    out[oi] = s;
  }
}

extern "C" void kernel_launch(void* const* d_in, const int* in_sizes, int n_in,
                              void* d_out, int out_size, void* d_ws, size_t ws_size,
                              hipStream_t stream){
  const float* x  = (const float*)d_in[0];
  const float* Wx = (const float*)d_in[1];
  const float* Wh = (const float*)d_in[2];
  const float* b  = (const float*)d_in[3];
  const float* W1 = (const float*)d_in[4];
  const float* b1 = (const float*)d_in[5];
  const float* W2 = (const float*)d_in[6];
  const float* b2 = (const float*)d_in[7];

  char* ws = (char*)d_ws;
  size_t o = 0;
  u32*            flags   = (u32*)(ws + o);            o += 1024;
  unsigned short* whT_hi  = (unsigned short*)(ws + o); o += (size_t)G4 * H_ * 2;
  unsigned short* whT_lo  = (unsigned short*)(ws + o); o += (size_t)G4 * H_ * 2;
  u32*            hbp     = (u32*)(ws + o);            o += (size_t)2 * B_ * H_ * 4;
  unsigned short* hs      = (unsigned short*)(ws + o); o += (size_t)B_ * T_ * H_ * 2;
  float*          partialT= (float*)(ws + o);          o += (size_t)256 * 256 * 128 * 4;
  float*          hiddenT = (float*)(ws + o);          o += (size_t)256 * 128 * 4;

  hipMemsetAsync(flags, 0, 1024, stream);
  hipLaunchKernelGGL(prep_wh, dim3(512), dim3(256), 0, stream, Wh, whT_hi, whT_lo);
  hipLaunchKernelGGL(scan_k,  dim3(NWG), dim3(256), 0, stream,
                     x, Wx, b, whT_hi, whT_lo, hbp, hs, flags);
  hipLaunchKernelGGL(mlp1_k,  dim3(256), dim3(256), 0, stream, hs, W1, partialT);
  hipLaunchKernelGGL(mlp2_k,  dim3(256), dim3(128), 0, stream, partialT, b1, hiddenT);
  hipLaunchKernelGGL(mlp3_k,  dim3(1),   dim3(256), 0, stream, hiddenT, W2, b2, (float*)d_out);
}

// Round 14
// 2238.515 us; speedup vs baseline: 2.0159x; 2.0159x over previous
//
#include <hip/hip_runtime.h>
#include <hip/hip_bf16.h>
#include <stdint.h>

#define B_  128
#define T_  784
#define H_  512
#define G4  2048
#define NC_ 10

#define GB 8     // batch groups (16 rows each)
#define GC 32    // column groups (16 h-cols each)
#define NWG (GB*GC)

typedef __bf16 bf16x8 __attribute__((ext_vector_type(8)));
typedef float  f32x4  __attribute__((ext_vector_type(4)));
typedef unsigned int       u32;
typedef unsigned long long u64;

static __device__ __forceinline__ float bf2f(unsigned short u){
  union { unsigned int i; float f; } v; v.i = ((unsigned int)u) << 16; return v.f;
}
static __device__ __forceinline__ unsigned short f2bf_rn(float f){
  union { float f; unsigned int i; } v; v.f = f;
  unsigned int x = v.i;
  unsigned int lsb = (x >> 16) & 1u;
  x += 0x7fffu + lsb;
  return (unsigned short)(x >> 16);
}

// fast gates: native v_exp_f32 / v_rcp_f32 (err ~1e-6; proven r3/r5/r9)
static __device__ __forceinline__ float fsig(float z){
  return __builtin_amdgcn_rcpf(1.f + __expf(-z));
}
static __device__ __forceinline__ float ftanh(float z){
  return 2.f * __builtin_amdgcn_rcpf(1.f + __expf(-2.f * z)) - 1.f;
}

// ---------------------------------------------------------------------------
// Prep: Wh [512][2048] f32 -> WhT_hi/lo [2048][512] bf16 planes (transposed).
// ---------------------------------------------------------------------------
__global__ void prep_wh(const float* __restrict__ Wh,
                        unsigned short* __restrict__ whT_hi,
                        unsigned short* __restrict__ whT_lo){
  int idx = blockIdx.x * blockDim.x + threadIdx.x;   // 0..131071
  int kb  = idx >> 11;        // 0..63  (k block of 8)
  int g   = idx & 2047;       // 0..2047 (lane-adjacent -> coalesced reads)
  int k0  = kb * 8;
  unsigned short hi8[8], lo8[8];
  #pragma unroll
  for (int j = 0; j < 8; ++j){
    float v = Wh[(size_t)(k0 + j) * G4 + g];
    unsigned short hi = f2bf_rn(v);
    hi8[j] = hi;
    lo8[j] = f2bf_rn(v - bf2f(hi));
  }
  *(uint4*)(whT_hi + (size_t)g * H_ + k0) = *(const uint4*)hi8;
  *(uint4*)(whT_lo + (size_t)g * H_ + k0) = *(const uint4*)lo8;
}

// ---------------------------------------------------------------------------
// Main recurrent scan — r9 protocol (proven 2.07 ms) with two local edits:
// (1) QUARTER-POLL: wave wv polls only its 8 producer WGs (cg in [8wv,8wv+8)).
//     WG-level safety preserved: barrier1 requires all 4 waves (jointly
//     covering all 32 producers) before gates/h-store; flag stays WG-level
//     after barrier2 -> drift<=1 transitive argument identical to r9.
// (2) v_perm_b32 unpack (2 ops vs 6; instruction proven in r10).
// ---------------------------------------------------------------------------
__global__ __launch_bounds__(256, 1) void scan_k(
    const float* __restrict__ x, const float* __restrict__ Wx,
    const float* __restrict__ bias,
    const unsigned short* __restrict__ whT_hi,
    const unsigned short* __restrict__ whT_lo,
    u32* __restrict__ hbp,               // [2][128][512] u32 = (hi<<16)|lo
    unsigned short* __restrict__ hs,     // [128][784][512] bf16
    u32* __restrict__ flags)             // [256] per-WG step flag
{
  const int wg  = blockIdx.x;
  const int bg  = wg & 7;          // batch group
  const int cg  = wg >> 3;         // column group
  const int b0  = bg * 16;
  const int c0  = cg * 16;
  const int tid = threadIdx.x;
  const int wv  = tid >> 6;
  const int lane = tid & 63;
  const int nl  = lane & 15;       // A-row / B-col index within tile
  const int kc  = lane >> 4;       // k-chunk (0..3)

  __shared__ float xs[16 * 784];                          // 50176 B
  __shared__ __align__(16) unsigned short hhi[16 * 512];  // 16384 B (swizzled)
  __shared__ __align__(16) unsigned short hlo[16 * 512];  // 16384 B
  __shared__ float zbuf[16][16][17];                      // 17408 B

  // preload x slice for our 16 batch rows (contiguous in global)
  for (int i = tid; i < 16 * 784; i += 256) xs[i] = x[(size_t)b0 * 784 + i];

  // Wh fragments resident in registers
  bf16x8 bhi[4][4], blo[4][4];
  #pragma unroll
  for (int q = 0; q < 4; ++q){
    const int gcol = q * 512 + c0 + nl;
    const unsigned short* ph = whT_hi + (size_t)gcol * H_;
    const unsigned short* pl = whT_lo + (size_t)gcol * H_;
    #pragma unroll
    for (int kkl = 0; kkl < 4; ++kkl){
      int ko = (wv * 4 + kkl) * 32 + kc * 8;
      bhi[q][kkl] = *(const bf16x8*)(ph + ko);
      blo[q][kkl] = *(const bf16x8*)(pl + ko);
    }
  }

  const int r_  = tid >> 4;
  const int cl_ = tid & 15;
  float wx4[4], bb4[4];
  #pragma unroll
  for (int q = 0; q < 4; ++q){
    wx4[q] = Wx[q * 512 + c0 + cl_];
    bb4[q] = bias[q * 512 + c0 + cl_];
  }
  float c_st = 0.f;

  u32* const myflag = flags + (bg * 32 + cg);
  const u32* const grpflags = flags + bg * 32;
  const u32* const qflagp   = grpflags + 8 * wv;   // this wave's 8 producers

  __syncthreads();

  for (int t = 0; t < T_; ++t){
    f32x4 zq[4];
    #pragma unroll
    for (int q = 0; q < 4; ++q) zq[q] = (f32x4){0.f, 0.f, 0.f, 0.f};

    if (t > 0){
      // ---- QUARTER-POLL: wait only for THIS wave's 8 producer WGs ----
      {
        int guard = 0;
        for (;;){
          u32 v = (u32)t;
          if (lane < 8)
            v = __hip_atomic_load(qflagp + lane, __ATOMIC_RELAXED, __HIP_MEMORY_SCOPE_AGENT);
          if (__all(v >= (u32)t)) break;
          if (++guard > (1 << 22)) break;   // fail loudly, never hang
        }
        asm volatile("" ::: "memory");      // keep data loads after the poll
      }

      // ---- stage h (packed u32) from LLC: thread -> cols {2tid,2tid+1} ----
      const u64* hb8 = (const u64*)(hbp + (size_t)(t & 1) * B_ * H_);
      u64 vv[16];
      #pragma unroll
      for (int j = 0; j < 16; ++j)
        vv[j] = __hip_atomic_load(hb8 + (size_t)(b0 + j) * 256 + tid,
                                  __ATOMIC_RELAXED, __HIP_MEMORY_SCOPE_AGENT);
      #pragma unroll
      for (int j = 0; j < 16; ++j){
        u32 a = (u32)vv[j], b = (u32)(vv[j] >> 32);
        u32 hip_, lop_;
        asm("v_perm_b32 %0, %1, %2, %3" : "=v"(hip_)
            : "v"(b), "v"(a), "s"(0x07060302u));   // {b.hi16, a.hi16}
        asm("v_perm_b32 %0, %1, %2, %3" : "=v"(lop_)
            : "v"(b), "v"(a), "s"(0x05040100u));   // {b.lo16, a.lo16}
        int off = (4 * tid) ^ ((j & 7) << 4);   // XOR swizzle, 4B-aligned safe
        *(u32*)((char*)hhi + j * 1024 + off) = hip_;
        *(u32*)((char*)hlo + j * 1024 + off) = lop_;
      }
      // wave wv stages exactly cols [128wv,128wv+128) = the only ones it reads.

      f32x4 ahh[4], ahl[4], alh[4];
      #pragma unroll
      for (int q = 0; q < 4; ++q){ ahh[q] = (f32x4){0,0,0,0}; ahl[q] = (f32x4){0,0,0,0}; alh[q] = (f32x4){0,0,0,0}; }

      const int base = nl * 1024;
      const int swz  = (nl & 7) << 4;
      #pragma unroll
      for (int kkl = 0; kkl < 4; ++kkl){
        int bo = (wv * 4 + kkl) * 64 + kc * 16;
        int ad = base + (bo ^ swz);
        bf16x8 ah = *(const bf16x8*)((const char*)hhi + ad);
        bf16x8 al = *(const bf16x8*)((const char*)hlo + ad);
        #pragma unroll
        for (int q = 0; q < 4; ++q){
          ahh[q] = __builtin_amdgcn_mfma_f32_16x16x32_bf16(ah, bhi[q][kkl], ahh[q], 0, 0, 0);
          ahl[q] = __builtin_amdgcn_mfma_f32_16x16x32_bf16(ah, blo[q][kkl], ahl[q], 0, 0, 0);
          alh[q] = __builtin_amdgcn_mfma_f32_16x16x32_bf16(al, bhi[q][kkl], alh[q], 0, 0, 0);
        }
      }
      #pragma unroll
      for (int q = 0; q < 4; ++q) zq[q] = ahh[q] + (ahl[q] + alh[q]);
    }

    // write K-partial z tiles: D layout col=lane&15, row=kc*4+i
    #pragma unroll
    for (int q = 0; q < 4; ++q){
      #pragma unroll
      for (int i = 0; i < 4; ++i) zbuf[wv * 4 + q][kc * 4 + i][nl] = zq[q][i];
    }
    __syncthreads();   // barrier1: all 4 waves arrived => all 32 producers >= t

    // gates (fp32, fast exp/rcp) -- each thread owns (b0+r_, c0+cl_)
    unsigned short hi_keep;
    {
      float xv = xs[r_ * 784 + t];
      float zf = zbuf[0][r_][cl_] + zbuf[4][r_][cl_] + zbuf[8][r_][cl_]  + zbuf[12][r_][cl_] + xv * wx4[0] + bb4[0];
      float zr = zbuf[1][r_][cl_] + zbuf[5][r_][cl_] + zbuf[9][r_][cl_]  + zbuf[13][r_][cl_] + xv * wx4[1] + bb4[1];
      float zu = zbuf[2][r_][cl_] + zbuf[6][r_][cl_] + zbuf[10][r_][cl_] + zbuf[14][r_][cl_] + xv * wx4[2] + bb4[2];
      float zo = zbuf[3][r_][cl_] + zbuf[7][r_][cl_] + zbuf[11][r_][cl_] + zbuf[15][r_][cl_] + xv * wx4[3] + bb4[3];
      float f  = fsig(zf);
      float r  = fsig(zr);
      float omf = 1.f - f;
      float g  = r * (1.f - omf * omf) + (1.f - r) * (f * f);
      c_st = g * c_st + (1.f - g) * ftanh(zu);
      float h = fsig(zo) * ftanh(c_st);
      unsigned short hi = f2bf_rn(h);
      unsigned short lo = f2bf_rn(h - bf2f(hi));
      hi_keep = hi;
      u32 packed = ((u32)hi << 16) | (u32)lo;
      // publish h(t+1) via device-coherent store (LLC), no fence needed
      __hip_atomic_store(hbp + (size_t)((t + 1) & 1) * B_ * H_ +
                               (size_t)(b0 + r_) * H_ + (c0 + cl_),
                         packed, __ATOMIC_RELAXED, __HIP_MEMORY_SCOPE_AGENT);
    }

    // barrier2 drains every wave's hb store (vmcnt(0) implied), then publish.
    __syncthreads();
    if (tid == 0)
      __hip_atomic_store(myflag, (u32)(t + 1), __ATOMIC_RELAXED, __HIP_MEMORY_SCOPE_AGENT);

    // hs store issued AFTER the flag barrier: drains under next step's work.
    hs[((size_t)(b0 + r_) * T_ + t) * H_ + (c0 + cl_)] = hi_keep;
  }
}

// ---------------------------------------------------------------------------
// MLP stage 1: partial GEMM, D[n][b] orientation. 256 WGs, K-chunk = 1568.
// ---------------------------------------------------------------------------
__global__ __launch_bounds__(256, 1) void mlp1_k(
    const unsigned short* __restrict__ hs,   // [128][401408] bf16
    const float* __restrict__ W1,            // [401408][256]
    float* __restrict__ partialT)            // [256 cm][256 n][128 b]
{
  const int cm  = blockIdx.x;
  const int tid = threadIdx.x;
  const int wv  = tid >> 6, lane = tid & 63;
  const int nl  = lane & 15, kc = lane >> 4;
  const int m_base = cm * 1568;

  f32x4 acc[4][8];
  #pragma unroll
  for (int i = 0; i < 4; ++i)
    #pragma unroll
    for (int j = 0; j < 8; ++j) acc[i][j] = (f32x4){0, 0, 0, 0};

  for (int ks = 0; ks < 49; ++ks){
    const int m0 = m_base + ks * 32 + kc * 8;
    bf16x8 bf[8];
    #pragma unroll
    for (int nt = 0; nt < 8; ++nt)
      bf[nt] = *(const bf16x8*)(hs + (size_t)(nt * 16 + nl) * 401408 + m0);

    #pragma unroll
    for (int mt = 0; mt < 4; ++mt){
      const int n = wv * 64 + mt * 16 + nl;
      union { bf16x8 v; unsigned short u[8]; } Ah, Al;
      #pragma unroll
      for (int j = 0; j < 8; ++j){
        float av = W1[(size_t)(m0 + j) * 256 + n];
        unsigned short hi = f2bf_rn(av);
        Ah.u[j] = hi;
        Al.u[j] = f2bf_rn(av - bf2f(hi));
      }
      #pragma unroll
      for (int nt = 0; nt < 8; ++nt){
        acc[mt][nt] = __builtin_amdgcn_mfma_f32_16x16x32_bf16(Ah.v, bf[nt], acc[mt][nt], 0, 0, 0);
        acc[mt][nt] = __builtin_amdgcn_mfma_f32_16x16x32_bf16(Al.v, bf[nt], acc[mt][nt], 0, 0, 0);
      }
    }
  }

  #pragma unroll
  for (int mt = 0; mt < 4; ++mt){
    const int n = wv * 64 + mt * 16 + kc * 4;
    #pragma unroll
    for (int nt = 0; nt < 8; ++nt){
      const int b = nt * 16 + nl;
      #pragma unroll
      for (int i = 0; i < 4; ++i)
        partialT[((size_t)cm * 256 + (n + i)) * 128 + b] = acc[mt][nt][i];
    }
  }
}

// MLP stage 2: reduce partials over 256 chunks, + b1, ReLU -> hiddenT [256][128]
__global__ void mlp2_k(const float* __restrict__ partialT,
                       const float* __restrict__ b1,
                       float* __restrict__ hiddenT){
  const int n = blockIdx.x;
  const int b = threadIdx.x;
  float s = 0.f;
  for (int cm = 0; cm < 256; ++cm)
    s += partialT[((size_t)cm * 256 + n) * 128 + b];
  s += b1[n];
  hiddenT[n * 128 + b] = s > 0.f ? s : 0.f;
}

// MLP stage 3: out[b][j] = b2[j] + sum_n hiddenT[n][b] * W2[n][j]
__global__ void mlp3_k(const float* __restrict__ hiddenT,
                       const float* __restrict__ W2,
                       const float* __restrict__ b2,
                       float* __restrict__ out){
  const int tid = threadIdx.x;
  for (int oi = tid; oi < B_ * NC_; oi += 256){
    int b = oi / NC_, j = oi % NC_;
    float s = b2[j];
    for (int n = 0; n < 256; ++n)
      s += hiddenT[n * 128 + b] * W2[n * NC_ + j];
    out[oi] = s;
  }
}

extern "C" void kernel_launch(void* const* d_in, const int* in_sizes, int n_in,
                              void* d_out, int out_size, void* d_ws, size_t ws_size,
                              hipStream_t stream){
  const float* x  = (const float*)d_in[0];
  const float* Wx = (const float*)d_in[1];
  const float* Wh = (const float*)d_in[2];
  const float* b  = (const float*)d_in[3];
  const float* W1 = (const float*)d_in[4];
  const float* b1 = (const float*)d_in[5];
  const float* W2 = (const float*)d_in[6];
  const float* b2 = (const float*)d_in[7];

  char* ws = (char*)d_ws;
  size_t o = 0;
  u32*            flags   = (u32*)(ws + o);            o += 1024;
  unsigned short* whT_hi  = (unsigned short*)(ws + o); o += (size_t)G4 * H_ * 2;
  unsigned short* whT_lo  = (unsigned short*)(ws + o); o += (size_t)G4 * H_ * 2;
  u32*            hbp     = (u32*)(ws + o);            o += (size_t)2 * B_ * H_ * 4;
  unsigned short* hs      = (unsigned short*)(ws + o); o += (size_t)B_ * T_ * H_ * 2;
  float*          partialT= (float*)(ws + o);          o += (size_t)256 * 256 * 128 * 4;
  float*          hiddenT = (float*)(ws + o);          o += (size_t)256 * 128 * 4;

  hipMemsetAsync(flags, 0, 1024, stream);
  hipLaunchKernelGGL(prep_wh, dim3(512), dim3(256), 0, stream, Wh, whT_hi, whT_lo);
  hipLaunchKernelGGL(scan_k,  dim3(NWG), dim3(256), 0, stream,
                     x, Wx, b, whT_hi, whT_lo, hbp, hs, flags);
  hipLaunchKernelGGL(mlp1_k,  dim3(256), dim3(256), 0, stream, hs, W1, partialT);
  hipLaunchKernelGGL(mlp2_k,  dim3(256), dim3(128), 0, stream, partialT, b1, hiddenT);
  hipLaunchKernelGGL(mlp3_k,  dim3(1),   dim3(256), 0, stream, hiddenT, W2, b2, (float*)d_out);
}